// Round 1
// baseline (269.227 us; speedup 1.0000x reference)
//
#include <hip/hip_runtime.h>
#include <stdint.h>

typedef __attribute__((ext_vector_type(4))) float  floatx4;   // MFMA C/D frag
typedef __attribute__((ext_vector_type(8))) short  shortx8;   // MFMA A/B frag (8 bf16)
typedef __attribute__((ext_vector_type(4))) unsigned short ushortx4;

typedef unsigned int   u32;
typedef unsigned short u16;

#define TILE    128
#define BK      64
#define THREADS 256
#define CHUNK   (TILE * BK)    // 8192 bf16 elems = 16 KB LDS per tile buffer

// ---- bf16 pack: +0x8000 round, take high halves via v_perm ----
__device__ __forceinline__ u32 pack2bf(float f0, float f1) {
    u32 u0 = __builtin_bit_cast(u32, f0) + 0x8000u;
    u32 u1 = __builtin_bit_cast(u32, f1) + 0x8000u;
    return __builtin_amdgcn_perm(u1, u0, 0x07060302u);  // {u1.hi16, u0.hi16}
}

__device__ __forceinline__ unsigned short f2bf(float f) {
    u32 u = __builtin_bit_cast(u32, f);
    u += 0x7FFFu + ((u >> 16) & 1u);
    return (unsigned short)(u >> 16);
}

// ============ prep (grid-stride, fully streaming): linear-in, linear-out ============
// At: x converted fp32->bf16, row-major [M][I].  Bt: W dequantized int4->bf16, row-major [O][I].
__global__ __launch_bounds__(THREADS)
void prep_kernel(const float* __restrict__ x, const int* __restrict__ pw,
                 const float* __restrict__ scale, const int* __restrict__ pzp,
                 u16* __restrict__ At, u16* __restrict__ Bt,
                 int M, int O, int I, int ng, int lsSeg, int lsG) {
    const int NT = gridDim.x * THREADS;
    const int t0 = blockIdx.x * THREADS + threadIdx.x;
    const int segsPerRow = I >> 3;

    // ---- x: fp32 -> bf16, 8 elems (32B in, 16B out) per unit, fully linear ----
    const int Sx = (M * I) >> 3;
    for (int s = t0; s < Sx; s += NT) {
        const float4 v0 = ((const float4*)x)[(size_t)s * 2];
        const float4 v1 = ((const float4*)x)[(size_t)s * 2 + 1];
        u32 p[4];
        p[0] = pack2bf(v0.x, v0.y); p[1] = pack2bf(v0.z, v0.w);
        p[2] = pack2bf(v1.x, v1.y); p[3] = pack2bf(v1.z, v1.w);
        ((uint4*)At)[s] = *(uint4*)p;
    }

    // ---- W: int4 -> bf16 dequant, one int32 word -> 16B out, fully linear ----
    const int Sw = (O * I) >> 3;
    for (int s = t0; s < Sw; s += NT) {
        const u32 wq = (u32)pw[s];
        const int o    = s >> lsSeg;
        const int wcol = s & (segsPerRow - 1);
        const int g    = wcol >> lsG;                 // 16 words per 128-k group
        const float sc = scale[o * ng + g];
        const int zpw  = pzp[o * ((ng + 7) >> 3) + (g >> 3)];
        const int zp   = (zpw >> ((g & 7) * 4)) & 15;
        const float nzc = -sc * (float)(zp + 128);
        float v[8];
        #pragma unroll
        for (int j = 0; j < 8; j++) {
            u32 tt;
            if (j < 4)       tt = (wq << (16 - 4 * j)) & 0x000F0000u;
            else if (j == 4) tt = wq & 0x000F0000u;
            else             tt = (wq >> (4 * j - 16)) & 0x000F0000u;
            v[j] = __builtin_fmaf(__builtin_bit_cast(float, tt | 0x43000000u), sc, nzc);  // (nib-zp)*s
        }
        u32 p[4];
        p[0] = pack2bf(v[0], v[1]); p[1] = pack2bf(v[2], v[3]);
        p[2] = pack2bf(v[4], v[5]); p[3] = pack2bf(v[6], v[7]);
        ((uint4*)Bt)[s] = *(uint4*)p;
    }
}

// ============ main GEMM: 2-deep LDS double-buffer, counted vmcnt (T3+T4 minimum) ============
// global_load_lds: LDS dest is lane-linear (required); global source per-lane address
// carries the XOR swizzle, so the LDS image equals the conflict-free layout.
// Pipeline: issue(next tile) -> s_waitcnt vmcnt(8) (cur tile's 8 loads done, next 8 stay
// in flight across the barrier) -> s_barrier -> compute(cur) -> s_barrier.
__global__ __launch_bounds__(THREADS, 2)
void gemm_bf16(const u16* __restrict__ At, const u16* __restrict__ Bt,
               const float* __restrict__ bias, float* __restrict__ out,
               int O, int I, int KT) {
    __shared__ u16 As[2][CHUNK];
    __shared__ u16 Bs[2][CHUNK];

    const int tid = threadIdx.x;
    const int nblk_n = O / TILE;
    const int mt = blockIdx.x / nblk_n;      // mt-major: A-stripe reuse clusters in time
    const int nt = blockIdx.x % nblk_n;
    const int w = tid >> 6, lane = tid & 63;
    const int wm = w >> 1, wn = w & 1;       // 2x2 wave grid, 64x64 per wave
    const int l15 = lane & 15, l4 = lane >> 4;
    const int sw  = l15 & 7;                 // un-swizzle XOR for frag reads

    // staging map: issue it stages rows it*32..it*32+31; thread t -> row it*32+(t>>3),
    // LDS chunk position t&7, fetching logical chunk (t&7) ^ (row&7). it*32 ≡ 0 (mod 8).
    const int sr = tid >> 3;
    const int sc = (tid & 7) ^ (sr & 7);

    floatx4 acc[4][4];
    #pragma unroll
    for (int i = 0; i < 4; i++)
        #pragma unroll
        for (int j = 0; j < 4; j++)
            acc[i][j] = (floatx4){0.f, 0.f, 0.f, 0.f};

    const u16* gaBase = At + ((size_t)(mt * TILE) + sr) * I + sc * 8;
    const u16* gbBase = Bt + ((size_t)(nt * TILE) + sr) * I + sc * 8;
    const int ldsOffBase = tid * 8;

    auto issue = [&](int buf, int kt) {
        const u16* ga = gaBase + kt * BK;
        const u16* gb = gbBase + kt * BK;
        #pragma unroll
        for (int it = 0; it < 4; it++) {
            const int ldsOff = it * 2048 + ldsOffBase;       // lane-linear 16B slots
            const size_t gOff = (size_t)(it * 32) * I;
            __builtin_amdgcn_global_load_lds((const __attribute__((address_space(1))) u32*)(ga + gOff),
                                             (__attribute__((address_space(3))) u32*)(&As[buf][ldsOff]),
                                             16, 0, 0);
            __builtin_amdgcn_global_load_lds((const __attribute__((address_space(1))) u32*)(gb + gOff),
                                             (__attribute__((address_space(3))) u32*)(&Bs[buf][ldsOff]),
                                             16, 0, 0);
        }
    };

    auto compute = [&](int buf) {
        const u16* asb = As[buf];
        const u16* bsb = Bs[buf];
        #pragma unroll
        for (int ks = 0; ks < 2; ks++) {
            shortx8 af[4], bfr[4];
            #pragma unroll
            for (int i = 0; i < 4; i++)
                af[i] = *(const shortx8*)(&asb[(wm * 64 + i * 16 + l15) * BK + ((ks * 4 + l4) ^ sw) * 8]);
            #pragma unroll
            for (int j = 0; j < 4; j++)
                bfr[j] = *(const shortx8*)(&bsb[(wn * 64 + j * 16 + l15) * BK + ((ks * 4 + l4) ^ sw) * 8]);
            #pragma unroll
            for (int i = 0; i < 4; i++)
                #pragma unroll
                for (int j = 0; j < 4; j++)
                    acc[i][j] = __builtin_amdgcn_mfma_f32_16x16x32_bf16(af[i], bfr[j], acc[i][j], 0, 0, 0);
        }
    };

    // prologue: stage tile 0 into buffer 0
    issue(0, 0);
    int cur = 0;
    for (int kt = 0; kt < KT - 1; kt++) {
        issue(cur ^ 1, kt + 1);                       // prefetch next tile (8 loads in flight)
        asm volatile("s_waitcnt vmcnt(8)" ::: "memory");  // cur tile's loads retired; next stays pending
        __builtin_amdgcn_s_barrier();                 // all waves: cur tile visible in LDS
        compute(cur);
        __builtin_amdgcn_s_barrier();                 // all waves done reading cur buffer
        cur ^= 1;
    }
    // epilogue tile: nothing left to prefetch -> full drain
    asm volatile("s_waitcnt vmcnt(0)" ::: "memory");
    __builtin_amdgcn_s_barrier();
    compute(cur);

    #pragma unroll
    for (int j = 0; j < 4; j++) {
        int col  = nt * TILE + wn * 64 + j * 16 + l15;
        float bv = bias[col];
        #pragma unroll
        for (int i = 0; i < 4; i++) {
            int rowb = mt * TILE + wm * 64 + i * 16 + l4 * 4;
            #pragma unroll
            for (int r = 0; r < 4; r++)
                out[(size_t)(rowb + r) * O + col] = acc[i][j][r] + bv;
        }
    }
}

// ======================= fallback (round-1 fused kernel) if ws too small =======================
#define LDA 72
__global__ __launch_bounds__(THREADS, 2)
void wql_fused(const float* __restrict__ x, const int* __restrict__ pw,
               const float* __restrict__ scale, const int* __restrict__ pzp,
               const float* __restrict__ bias, float* __restrict__ out,
               int M, int O, int I, int ng)
{
    __shared__ unsigned short As[TILE * LDA];
    __shared__ unsigned short Bs[TILE * LDA];
    const int tid = threadIdx.x;
    const int nblk_n = O / TILE;
    const int mt = blockIdx.x / nblk_n, nt = blockIdx.x % nblk_n;
    const int w = tid >> 6, lane = tid & 63;
    const int wm = w >> 1, wn = w & 1;
    const int l15 = lane & 15, l4 = lane >> 4;
    const int pw_rowlen = I / 8, zp_rowlen = (ng + 7) / 8, GS = I / ng;

    floatx4 acc[4][4];
    #pragma unroll
    for (int i = 0; i < 4; i++)
        #pragma unroll
        for (int j = 0; j < 4; j++) acc[i][j] = (floatx4){0.f, 0.f, 0.f, 0.f};

    const int nk = I / BK;
    for (int kt = 0; kt < nk; kt++) {
        __syncthreads();
        #pragma unroll
        for (int it = 0; it < 8; it++) {
            int f = tid + it * THREADS;
            int row = f >> 4, seg = f & 15;
            const float4 v = *(const float4*)(x + (size_t)(mt * TILE + row) * I + kt * BK + seg * 4);
            ushortx4 b;
            b.x = f2bf(v.x); b.y = f2bf(v.y); b.z = f2bf(v.z); b.w = f2bf(v.w);
            *(ushortx4*)(&As[row * LDA + seg * 4]) = b;
        }
        const int g = (kt * BK) / GS;
        #pragma unroll
        for (int it = 0; it < 4; it++) {
            int e = tid + it * THREADS;
            int row = e >> 3, c = e & 7;
            int o = nt * TILE + row;
            int wq = pw[(size_t)o * pw_rowlen + kt * (BK / 8) + c];
            float s = scale[o * ng + g];
            int zpw = pzp[o * zp_rowlen + (g >> 3)];
            int zp = (zpw >> ((g & 7) * 4)) & 15;
            shortx8 b;
            #pragma unroll
            for (int j = 0; j < 8; j++) {
                int nib = (wq >> (4 * j)) & 15;
                b[j] = (short)f2bf((float)(nib - zp) * s);
            }
            *(shortx8*)(&Bs[row * LDA + c * 8]) = b;
        }
        __syncthreads();
        #pragma unroll
        for (int ks = 0; ks < 2; ks++) {
            shortx8 af[4], bfr[4];
            #pragma unroll
            for (int i = 0; i < 4; i++)
                af[i] = *(const shortx8*)(&As[(wm * 64 + i * 16 + l15) * LDA + ks * 32 + l4 * 8]);
            #pragma unroll
            for (int j = 0; j < 4; j++)
                bfr[j] = *(const shortx8*)(&Bs[(wn * 64 + j * 16 + l15) * LDA + ks * 32 + l4 * 8]);
            #pragma unroll
            for (int i = 0; i < 4; i++)
                #pragma unroll
                for (int j = 0; j < 4; j++)
                    acc[i][j] = __builtin_amdgcn_mfma_f32_16x16x32_bf16(af[i], bfr[j], acc[i][j], 0, 0, 0);
        }
    }
    #pragma unroll
    for (int j = 0; j < 4; j++) {
        int col = nt * TILE + wn * 64 + j * 16 + l15;
        float bv = bias[col];
        #pragma unroll
        for (int i = 0; i < 4; i++) {
            int rowb = mt * TILE + wm * 64 + i * 16 + l4 * 4;
            #pragma unroll
            for (int r = 0; r < 4; r++)
                out[(size_t)(rowb + r) * O + col] = acc[i][j][r] + bv;
        }
    }
}

extern "C" void kernel_launch(void* const* d_in, const int* in_sizes, int n_in,
                              void* d_out, int out_size, void* d_ws, size_t ws_size,
                              hipStream_t stream) {
    const float* x     = (const float*)d_in[0];
    const int*   pw    = (const int*)d_in[1];
    const float* scale = (const float*)d_in[2];
    const int*   pzp   = (const int*)d_in[3];
    const float* bias  = (const float*)d_in[4];
    float*       out   = (float*)d_out;

    const int O  = in_sizes[4];                   // 4096
    const int ng = in_sizes[2] / O;               // 32
    const int I  = (in_sizes[1] / O) * 8;         // 4096
    const int M  = in_sizes[0] / I;               // 4096
    const int KT = I / BK;                        // 64
    int lsSeg = 0; { int v = I >> 3; while ((1 << lsSeg) < v) lsSeg++; }      // log2(I/8)
    int lsG = 0;   { int v = (I / ng) >> 3; while ((1 << lsG) < v) lsG++; }   // log2(GS/8)

    const size_t need = ((size_t)M * I + (size_t)O * I) * sizeof(u16);  // 64 MB
    if (ws_size >= need) {
        u16* At = (u16*)d_ws;
        u16* Bt = At + (size_t)M * I;
        prep_kernel<<<dim3(2048), THREADS, 0, stream>>>(x, pw, scale, pzp, At, Bt, M, O, I, ng, lsSeg, lsG);
        gemm_bf16<<<dim3((M / TILE) * (O / TILE)), THREADS, 0, stream>>>(At, Bt, bias, out, O, I, KT);
    } else {
        wql_fused<<<dim3((M / TILE) * (O / TILE)), THREADS, 0, stream>>>(x, pw, scale, pzp, bias, out, M, O, I, ng);
    }
}

// Round 2
// 257.121 us; speedup vs baseline: 1.0471x; 1.0471x over previous
//
#include <hip/hip_runtime.h>
#include <stdint.h>

typedef __attribute__((ext_vector_type(4))) float  floatx4;   // MFMA C/D frag
typedef __attribute__((ext_vector_type(8))) short  shortx8;   // MFMA A/B frag (8 bf16)
typedef __attribute__((ext_vector_type(4))) unsigned short ushortx4;

typedef unsigned int   u32;
typedef unsigned short u16;

#define TILE    128
#define BK      64
#define THREADS 256
#define CHUNK   (TILE * BK)    // 8192 bf16 elems = 16 KB LDS per tile

// ---- bf16 pack: +0x8000 round, take high halves via v_perm ----
__device__ __forceinline__ u32 pack2bf(float f0, float f1) {
    u32 u0 = __builtin_bit_cast(u32, f0) + 0x8000u;
    u32 u1 = __builtin_bit_cast(u32, f1) + 0x8000u;
    return __builtin_amdgcn_perm(u1, u0, 0x07060302u);  // {u1.hi16, u0.hi16}
}

__device__ __forceinline__ unsigned short f2bf(float f) {
    u32 u = __builtin_bit_cast(u32, f);
    u += 0x7FFFu + ((u >> 16) & 1u);
    return (unsigned short)(u >> 16);
}

// ============ prep (grid-stride, fully streaming): linear-in, linear-out ============
__global__ __launch_bounds__(THREADS)
void prep_kernel(const float* __restrict__ x, const int* __restrict__ pw,
                 const float* __restrict__ scale, const int* __restrict__ pzp,
                 u16* __restrict__ At, u16* __restrict__ Bt,
                 int M, int O, int I, int ng, int lsSeg, int lsG) {
    const int NT = gridDim.x * THREADS;
    const int t0 = blockIdx.x * THREADS + threadIdx.x;
    const int segsPerRow = I >> 3;

    const int Sx = (M * I) >> 3;
    for (int s = t0; s < Sx; s += NT) {
        const float4 v0 = ((const float4*)x)[(size_t)s * 2];
        const float4 v1 = ((const float4*)x)[(size_t)s * 2 + 1];
        u32 p[4];
        p[0] = pack2bf(v0.x, v0.y); p[1] = pack2bf(v0.z, v0.w);
        p[2] = pack2bf(v1.x, v1.y); p[3] = pack2bf(v1.z, v1.w);
        ((uint4*)At)[s] = *(uint4*)p;
    }

    const int Sw = (O * I) >> 3;
    for (int s = t0; s < Sw; s += NT) {
        const u32 wq = (u32)pw[s];
        const int o    = s >> lsSeg;
        const int wcol = s & (segsPerRow - 1);
        const int g    = wcol >> lsG;
        const float sc = scale[o * ng + g];
        const int zpw  = pzp[o * ((ng + 7) >> 3) + (g >> 3)];
        const int zp   = (zpw >> ((g & 7) * 4)) & 15;
        const float nzc = -sc * (float)(zp + 128);
        float v[8];
        #pragma unroll
        for (int j = 0; j < 8; j++) {
            u32 tt;
            if (j < 4)       tt = (wq << (16 - 4 * j)) & 0x000F0000u;
            else if (j == 4) tt = wq & 0x000F0000u;
            else             tt = (wq >> (4 * j - 16)) & 0x000F0000u;
            v[j] = __builtin_fmaf(__builtin_bit_cast(float, tt | 0x43000000u), sc, nzc);
        }
        u32 p[4];
        p[0] = pack2bf(v[0], v[1]); p[1] = pack2bf(v[2], v[3]);
        p[2] = pack2bf(v[4], v[5]); p[3] = pack2bf(v[6], v[7]);
        ((uint4*)Bt)[s] = *(uint4*)p;
    }
}

// ===================== 256x256 phase-interleaved GEMM, 4-buffer ring =====================
// LDS per buffer: 256 rows x 128 B; row = 8 x 16B chunk slots. Logical chunk k (0-3 = A
// cols k*8..k*8+7 of this K-tile; 4-7 = B) stored at slot k ^ (row&7). global_load_lds
// dest is lane-linear; the swizzle is carried by the per-lane GLOBAL source address.
// Ring: compute tile t from buf t&3 while staging tile t+3 into buf (t+3)&3 (last read
// at tile t-1, closed by barrier). Boundary wait vmcnt(8): tiles t+2,t+3 stay in flight.
#define VM8 asm volatile("s_waitcnt vmcnt(8)" ::: "memory")
#define VM4 asm volatile("s_waitcnt vmcnt(4)" ::: "memory")
#define VM0 asm volatile("s_waitcnt vmcnt(0)" ::: "memory")

#define GTILE(T, DOISS, WAITSTMT) do {                                                    \
    const u16* __restrict__ sb = &S[((T) & 3) * 16384];                                   \
    u16* nb = &S[(((T) + 3) & 3) * 16384];                                                \
    shortx8 af[4], bfr[4];                                                                \
    _Pragma("unroll")                                                                     \
    for (int i = 0; i < 4; i++) af[i]  = *(const shortx8*)(sb + rdA + i * 1024);          \
    _Pragma("unroll")                                                                     \
    for (int j = 0; j < 4; j++) bfr[j] = *(const shortx8*)(sb + rdB + j * 1024);          \
    if (DOISS) {                                                                          \
        _Pragma("unroll")                                                                 \
        for (int l = 0; l < 2; l++)                                                       \
            __builtin_amdgcn_global_load_lds((const __attribute__((address_space(1))) u32*)(g[l]), \
                (__attribute__((address_space(3))) u32*)(nb + ldsoff[l]), 16, 0, 0);      \
    }                                                                                     \
    __builtin_amdgcn_s_barrier();                                                         \
    __builtin_amdgcn_s_setprio(1);                                                        \
    _Pragma("unroll")                                                                     \
    for (int i = 0; i < 4; i++)                                                           \
        _Pragma("unroll")                                                                 \
        for (int j = 0; j < 4; j++)                                                       \
            acc[i][j] = __builtin_amdgcn_mfma_f32_16x16x32_bf16(af[i], bfr[j], acc[i][j], 0, 0, 0); \
    __builtin_amdgcn_s_setprio(0);                                                        \
    __builtin_amdgcn_s_barrier();                                                         \
    _Pragma("unroll")                                                                     \
    for (int i = 0; i < 4; i++) af[i] = *(const shortx8*)(sb + rdA + 4096 + i * 1024);    \
    if (DOISS) {                                                                          \
        _Pragma("unroll")                                                                 \
        for (int l = 2; l < 4; l++)                                                       \
            __builtin_amdgcn_global_load_lds((const __attribute__((address_space(1))) u32*)(g[l]), \
                (__attribute__((address_space(3))) u32*)(nb + ldsoff[l]), 16, 0, 0);      \
        _Pragma("unroll")                                                                 \
        for (int l = 0; l < 4; l++) g[l] += 32;                                           \
    }                                                                                     \
    __builtin_amdgcn_s_barrier();                                                         \
    __builtin_amdgcn_s_setprio(1);                                                        \
    _Pragma("unroll")                                                                     \
    for (int i = 0; i < 4; i++)                                                           \
        _Pragma("unroll")                                                                 \
        for (int j = 0; j < 4; j++)                                                       \
            acc[i + 4][j] = __builtin_amdgcn_mfma_f32_16x16x32_bf16(af[i], bfr[j], acc[i + 4][j], 0, 0, 0); \
    __builtin_amdgcn_s_setprio(0);                                                        \
    WAITSTMT;                                                                             \
    __builtin_amdgcn_s_barrier();                                                         \
} while (0)

__global__ __launch_bounds__(512, 2)
void gemm256(const u16* __restrict__ At, const u16* __restrict__ Bt,
             const float* __restrict__ bias, float* __restrict__ out,
             int O, int I, int KT) {
    __shared__ u16 S[4 * 16384];          // 128 KiB: 4-buffer ring

    const int tid = threadIdx.x;
    const int nblk_n = O / 256;

    // bijective XCD swizzle (grid is 256 = 8*32 here): XCD x gets 2 contiguous mt rows
    int bid = blockIdx.x;
    const int nwg = gridDim.x;
    if ((nwg & 7) == 0) {
        const int q = nwg >> 3;
        bid = (bid & 7) * q + (bid >> 3);
    }
    const int mt = bid / nblk_n, nt = bid % nblk_n;

    const int w = tid >> 6, lane = tid & 63;
    const int wm = w >> 2, wn = w & 3;        // 2x4 wave grid; wave owns 128(M) x 64(O)
    const int l15 = lane & 15, l4 = lane >> 4;
    const int sw  = l15 & 7;                  // read-side un-swizzle

    // ds_read base offsets (u16 units) within a buffer; row stride = 64 u16 (128 B)
    const int rdA = (wm * 128 + l15) * 64 + ((l4 ^ sw) * 8);
    const int rdB = (wn * 64  + l15) * 64 + ((((l4 | 4) ^ sw)) * 8);

    // staging: 4 loads/thread/tile; load l covers chunk-slot s = (w*4+l)*64 + lane.
    // slot -> (row = s>>3, pslot = s&7); logical chunk k = pslot ^ (row&7);
    // k<4 -> A chunk k of row; k>=4 -> B chunk k-4. Global addr carries the swizzle.
    const u16* g[4];
    int ldsoff[4];
    #pragma unroll
    for (int l = 0; l < 4; l++) {
        const int s   = (w * 4 + l) * 64 + lane;
        const int row = s >> 3;
        const int k   = (s & 7) ^ (row & 7);
        ldsoff[l] = (w * 4 + l) * 512 + lane * 8;      // lane-linear 16B slots (u16 units)
        g[l] = (k < 4) ? (At + (size_t)(mt * 256 + row) * I + k * 8)
                       : (Bt + (size_t)(nt * 256 + row) * I + (k - 4) * 8);
    }

    floatx4 acc[8][4];
    #pragma unroll
    for (int i = 0; i < 8; i++)
        #pragma unroll
        for (int j = 0; j < 4; j++)
            acc[i][j] = (floatx4){0.f, 0.f, 0.f, 0.f};

    // prologue: stage tiles 0,1,2 (12 loads/thread); wait tile 0 (8 stay in flight)
    #pragma unroll
    for (int p = 0; p < 3; p++) {
        u16* sb = &S[p * 16384];
        #pragma unroll
        for (int l = 0; l < 4; l++)
            __builtin_amdgcn_global_load_lds((const __attribute__((address_space(1))) u32*)(g[l]),
                (__attribute__((address_space(3))) u32*)(sb + ldsoff[l]), 16, 0, 0);
        #pragma unroll
        for (int l = 0; l < 4; l++) g[l] += 32;
    }
    VM8;
    __builtin_amdgcn_s_barrier();

    int t = 0;
    for (; t < KT - 3; ++t) GTILE(t, 1, VM8);
    GTILE(t, 0, VM4); ++t;       // KT-3: need KT-2 resident, KT-1 stays in flight
    GTILE(t, 0, VM0); ++t;       // KT-2: drain tail
    GTILE(t, 0, (void)0);        // KT-1

    #pragma unroll
    for (int j = 0; j < 4; j++) {
        int col  = nt * 256 + wn * 64 + j * 16 + l15;
        float bv = bias[col];
        #pragma unroll
        for (int i = 0; i < 8; i++) {
            int rowb = mt * 256 + wm * 128 + i * 16 + l4 * 4;
            #pragma unroll
            for (int r = 0; r < 4; r++)
                out[(size_t)(rowb + r) * O + col] = acc[i][j][r] + bv;
        }
    }
}

// ============ round-0 128x128 single-buffer GEMM (shape fallback, proven 130 us) ============
__global__ __launch_bounds__(THREADS, 2)
void gemm_bf16(const u16* __restrict__ At, const u16* __restrict__ Bt,
               const float* __restrict__ bias, float* __restrict__ out,
               int O, int I, int KT) {
    __shared__ u16 As[CHUNK];
    __shared__ u16 Bs[CHUNK];

    const int tid = threadIdx.x;
    const int nblk_n = O / TILE;
    const int mt = blockIdx.x / nblk_n;
    const int nt = blockIdx.x % nblk_n;
    const int w = tid >> 6, lane = tid & 63;
    const int wm = w >> 1, wn = w & 1;
    const int l15 = lane & 15, l4 = lane >> 4;
    const int sw  = l15 & 7;

    const int sr = tid >> 3;
    const int sc = (tid & 7) ^ (sr & 7);

    floatx4 acc[4][4];
    #pragma unroll
    for (int i = 0; i < 4; i++)
        #pragma unroll
        for (int j = 0; j < 4; j++)
            acc[i][j] = (floatx4){0.f, 0.f, 0.f, 0.f};

    const u16* gaBase = At + ((size_t)(mt * TILE) + sr) * I + sc * 8;
    const u16* gbBase = Bt + ((size_t)(nt * TILE) + sr) * I + sc * 8;

    for (int kt = 0; kt < KT; kt++) {
        const u16* ga = gaBase + kt * BK;
        const u16* gb = gbBase + kt * BK;
        __syncthreads();
        #pragma unroll
        for (int it = 0; it < 4; it++) {
            const int ldsOff = it * 2048 + tid * 8;
            const size_t gOff = (size_t)(it * 32) * I;
            __builtin_amdgcn_global_load_lds((const __attribute__((address_space(1))) u32*)(ga + gOff),
                                             (__attribute__((address_space(3))) u32*)(As + ldsOff),
                                             16, 0, 0);
            __builtin_amdgcn_global_load_lds((const __attribute__((address_space(1))) u32*)(gb + gOff),
                                             (__attribute__((address_space(3))) u32*)(Bs + ldsOff),
                                             16, 0, 0);
        }
        __syncthreads();

        #pragma unroll
        for (int ks = 0; ks < 2; ks++) {
            shortx8 af[4], bfr[4];
            #pragma unroll
            for (int i = 0; i < 4; i++)
                af[i] = *(const shortx8*)(&As[(wm * 64 + i * 16 + l15) * BK + ((ks * 4 + l4) ^ sw) * 8]);
            #pragma unroll
            for (int j = 0; j < 4; j++)
                bfr[j] = *(const shortx8*)(&Bs[(wn * 64 + j * 16 + l15) * BK + ((ks * 4 + l4) ^ sw) * 8]);
            #pragma unroll
            for (int i = 0; i < 4; i++)
                #pragma unroll
                for (int j = 0; j < 4; j++)
                    acc[i][j] = __builtin_amdgcn_mfma_f32_16x16x32_bf16(af[i], bfr[j], acc[i][j], 0, 0, 0);
        }
    }

    #pragma unroll
    for (int j = 0; j < 4; j++) {
        int col  = nt * TILE + wn * 64 + j * 16 + l15;
        float bv = bias[col];
        #pragma unroll
        for (int i = 0; i < 4; i++) {
            int rowb = mt * TILE + wm * 64 + i * 16 + l4 * 4;
            #pragma unroll
            for (int r = 0; r < 4; r++)
                out[(size_t)(rowb + r) * O + col] = acc[i][j][r] + bv;
        }
    }
}

// ======================= fallback (fused) if ws too small =======================
#define LDA 72
__global__ __launch_bounds__(THREADS, 2)
void wql_fused(const float* __restrict__ x, const int* __restrict__ pw,
               const float* __restrict__ scale, const int* __restrict__ pzp,
               const float* __restrict__ bias, float* __restrict__ out,
               int M, int O, int I, int ng)
{
    __shared__ unsigned short As[TILE * LDA];
    __shared__ unsigned short Bs[TILE * LDA];
    const int tid = threadIdx.x;
    const int nblk_n = O / TILE;
    const int mt = blockIdx.x / nblk_n, nt = blockIdx.x % nblk_n;
    const int w = tid >> 6, lane = tid & 63;
    const int wm = w >> 1, wn = w & 1;
    const int l15 = lane & 15, l4 = lane >> 4;
    const int pw_rowlen = I / 8, zp_rowlen = (ng + 7) / 8, GS = I / ng;

    floatx4 acc[4][4];
    #pragma unroll
    for (int i = 0; i < 4; i++)
        #pragma unroll
        for (int j = 0; j < 4; j++) acc[i][j] = (floatx4){0.f, 0.f, 0.f, 0.f};

    const int nk = I / BK;
    for (int kt = 0; kt < nk; kt++) {
        __syncthreads();
        #pragma unroll
        for (int it = 0; it < 8; it++) {
            int f = tid + it * THREADS;
            int row = f >> 4, seg = f & 15;
            const float4 v = *(const float4*)(x + (size_t)(mt * TILE + row) * I + kt * BK + seg * 4);
            ushortx4 b;
            b.x = f2bf(v.x); b.y = f2bf(v.y); b.z = f2bf(v.z); b.w = f2bf(v.w);
            *(ushortx4*)(&As[row * LDA + seg * 4]) = b;
        }
        const int g = (kt * BK) / GS;
        #pragma unroll
        for (int it = 0; it < 4; it++) {
            int e = tid + it * THREADS;
            int row = e >> 3, c = e & 7;
            int o = nt * TILE + row;
            int wq = pw[(size_t)o * pw_rowlen + kt * (BK / 8) + c];
            float s = scale[o * ng + g];
            int zpw = pzp[o * zp_rowlen + (g >> 3)];
            int zp = (zpw >> ((g & 7) * 4)) & 15;
            shortx8 b;
            #pragma unroll
            for (int j = 0; j < 8; j++) {
                int nib = (wq >> (4 * j)) & 15;
                b[j] = (short)f2bf((float)(nib - zp) * s);
            }
            *(shortx8*)(&Bs[row * LDA + c * 8]) = b;
        }
        __syncthreads();
        #pragma unroll
        for (int ks = 0; ks < 2; ks++) {
            shortx8 af[4], bfr[4];
            #pragma unroll
            for (int i = 0; i < 4; i++)
                af[i] = *(const shortx8*)(&As[(wm * 64 + i * 16 + l15) * LDA + ks * 32 + l4 * 8]);
            #pragma unroll
            for (int j = 0; j < 4; j++)
                bfr[j] = *(const shortx8*)(&Bs[(wn * 64 + j * 16 + l15) * LDA + ks * 32 + l4 * 8]);
            #pragma unroll
            for (int i = 0; i < 4; i++)
                #pragma unroll
                for (int j = 0; j < 4; j++)
                    acc[i][j] = __builtin_amdgcn_mfma_f32_16x16x32_bf16(af[i], bfr[j], acc[i][j], 0, 0, 0);
        }
    }
    #pragma unroll
    for (int j = 0; j < 4; j++) {
        int col = nt * TILE + wn * 64 + j * 16 + l15;
        float bv = bias[col];
        #pragma unroll
        for (int i = 0; i < 4; i++) {
            int rowb = mt * TILE + wm * 64 + i * 16 + l4 * 4;
            #pragma unroll
            for (int r = 0; r < 4; r++)
                out[(size_t)(rowb + r) * O + col] = acc[i][j][r] + bv;
        }
    }
}

extern "C" void kernel_launch(void* const* d_in, const int* in_sizes, int n_in,
                              void* d_out, int out_size, void* d_ws, size_t ws_size,
                              hipStream_t stream) {
    const float* x     = (const float*)d_in[0];
    const int*   pw    = (const int*)d_in[1];
    const float* scale = (const float*)d_in[2];
    const int*   pzp   = (const int*)d_in[3];
    const float* bias  = (const float*)d_in[4];
    float*       out   = (float*)d_out;

    const int O  = in_sizes[4];                   // 4096
    const int ng = in_sizes[2] / O;               // 32
    const int I  = (in_sizes[1] / O) * 8;         // 4096
    const int M  = in_sizes[0] / I;               // 4096
    int lsSeg = 0; { int v = I >> 3; while ((1 << lsSeg) < v) lsSeg++; }      // log2(I/8)
    int lsG = 0;   { int v = (I / ng) >> 3; while ((1 << lsG) < v) lsG++; }   // log2(GS/8)

    const size_t need = ((size_t)M * I + (size_t)O * I) * sizeof(u16);  // 64 MB
    if (ws_size >= need) {
        u16* At = (u16*)d_ws;
        u16* Bt = At + (size_t)M * I;
        prep_kernel<<<dim3(2048), THREADS, 0, stream>>>(x, pw, scale, pzp, At, Bt, M, O, I, ng, lsSeg, lsG);
        const bool ok256 = (M % 256 == 0) && (O % 256 == 0) && (I % 32 == 0) && (I / 32 >= 8);
        if (ok256) {
            gemm256<<<dim3((M / 256) * (O / 256)), 512, 0, stream>>>(At, Bt, bias, out, O, I, I / 32);
        } else {
            gemm_bf16<<<dim3((M / TILE) * (O / TILE)), THREADS, 0, stream>>>(At, Bt, bias, out, O, I, I / BK);
        }
    } else {
        wql_fused<<<dim3((M / TILE) * (O / TILE)), THREADS, 0, stream>>>(x, pw, scale, pzp, bias, out, M, O, I, ng);
    }
}

// Round 3
// 243.768 us; speedup vs baseline: 1.1044x; 1.0548x over previous
//
#include <hip/hip_runtime.h>
#include <stdint.h>

typedef __attribute__((ext_vector_type(4))) float  floatx4;   // MFMA C/D frag
typedef __attribute__((ext_vector_type(8))) short  shortx8;   // MFMA A/B frag (8 bf16)
typedef __attribute__((ext_vector_type(4))) unsigned short ushortx4;

typedef unsigned int   u32;
typedef unsigned short u16;

#define TILE    128
#define BK      64
#define THREADS 256
#define CHUNK   (TILE * BK)    // 8192 bf16 elems = 16 KB LDS per tile

// ---- bf16 pack: +0x8000 round, take high halves via v_perm ----
__device__ __forceinline__ u32 pack2bf(float f0, float f1) {
    u32 u0 = __builtin_bit_cast(u32, f0) + 0x8000u;
    u32 u1 = __builtin_bit_cast(u32, f1) + 0x8000u;
    return __builtin_amdgcn_perm(u1, u0, 0x07060302u);  // {u1.hi16, u0.hi16}
}

__device__ __forceinline__ unsigned short f2bf(float f) {
    u32 u = __builtin_bit_cast(u32, f);
    u += 0x7FFFu + ((u >> 16) & 1u);
    return (unsigned short)(u >> 16);
}

// ============ prep (grid-stride, fully streaming): linear-in, linear-out ============
__global__ __launch_bounds__(THREADS)
void prep_kernel(const float* __restrict__ x, const int* __restrict__ pw,
                 const float* __restrict__ scale, const int* __restrict__ pzp,
                 u16* __restrict__ At, u16* __restrict__ Bt,
                 int M, int O, int I, int ng, int lsSeg, int lsG) {
    const int NT = gridDim.x * THREADS;
    const int t0 = blockIdx.x * THREADS + threadIdx.x;
    const int segsPerRow = I >> 3;

    const int Sx = (M * I) >> 3;
    for (int s = t0; s < Sx; s += NT) {
        const float4 v0 = ((const float4*)x)[(size_t)s * 2];
        const float4 v1 = ((const float4*)x)[(size_t)s * 2 + 1];
        u32 p[4];
        p[0] = pack2bf(v0.x, v0.y); p[1] = pack2bf(v0.z, v0.w);
        p[2] = pack2bf(v1.x, v1.y); p[3] = pack2bf(v1.z, v1.w);
        ((uint4*)At)[s] = *(uint4*)p;
    }

    const int Sw = (O * I) >> 3;
    for (int s = t0; s < Sw; s += NT) {
        const u32 wq = (u32)pw[s];
        const int o    = s >> lsSeg;
        const int wcol = s & (segsPerRow - 1);
        const int g    = wcol >> lsG;
        const float sc = scale[o * ng + g];
        const int zpw  = pzp[o * ((ng + 7) >> 3) + (g >> 3)];
        const int zp   = (zpw >> ((g & 7) * 4)) & 15;
        const float nzc = -sc * (float)(zp + 128);
        float v[8];
        #pragma unroll
        for (int j = 0; j < 8; j++) {
            u32 tt;
            if (j < 4)       tt = (wq << (16 - 4 * j)) & 0x000F0000u;
            else if (j == 4) tt = wq & 0x000F0000u;
            else             tt = (wq >> (4 * j - 16)) & 0x000F0000u;
            v[j] = __builtin_fmaf(__builtin_bit_cast(float, tt | 0x43000000u), sc, nzc);
        }
        u32 p[4];
        p[0] = pack2bf(v[0], v[1]); p[1] = pack2bf(v[2], v[3]);
        p[2] = pack2bf(v[4], v[5]); p[3] = pack2bf(v[6], v[7]);
        ((uint4*)Bt)[s] = *(uint4*)p;
    }
}

// ===================== 256x256 register-pipelined GEMM, 4-buffer ring =====================
// LDS buffer = 256 rows x 128 B; row = [A chunks 0-3 | B chunks 0-3] of 16 B, stored at
// slot k ^ (row&7) (swizzle carried on the per-lane GLOBAL source; LDS dest lane-linear).
// Ring: compute tile t from buf t&3 while staging tile t+3 into buf (t+3)&3.
// Register pipeline (one-phase skew): each inter-barrier region does
//   { ds_read frags for NEXT phase  ->  issue DMA  ->  MFMA of CURRENT phase (regs) }
// so the LDS read burst drains under the MFMA cluster instead of serializing with it.
// Cross-wave WAR (DMA re-staging a buffer vs in-flight ds_read of it) is closed by the
// lgkmcnt(0) folded into the once-per-tile s_waitcnt before the end-of-tile barrier.

#define VM8L asm volatile("s_waitcnt vmcnt(8) lgkmcnt(0)" ::: "memory")
#define VM4L asm volatile("s_waitcnt vmcnt(4) lgkmcnt(0)" ::: "memory")
#define VM0L asm volatile("s_waitcnt vmcnt(0) lgkmcnt(0)" ::: "memory")

#define ISSUE(GP, NB, LO)                                                                  \
    __builtin_amdgcn_global_load_lds((const __attribute__((address_space(1))) u32*)(GP),   \
        (__attribute__((address_space(3))) u32*)((NB) + (LO)), 16, 0, 0)

// Region 1 of tile T (buf BUFC, parity P): read aflo/bfr of tile T; issue DMA loads 0,1
// for tile T+3 (buf BUFN); MFMA phase (T-1, hi-half) from parity P^1 registers.
#define R1(BUFC, BUFN, P, DOISS, DOMFMA) do {                                              \
    const u16* __restrict__ sb = S + (BUFC) * 16384;                                       \
    u16* nb = S + (BUFN) * 16384;                                                          \
    _Pragma("unroll")                                                                      \
    for (int i = 0; i < 4; i++) aflo[P][i] = *(const shortx8*)(sb + rdA + i * 1024);       \
    _Pragma("unroll")                                                                      \
    for (int j = 0; j < 4; j++) bfr[P][j]  = *(const shortx8*)(sb + rdB + j * 1024);       \
    if (DOISS) { ISSUE(g[0], nb, ldsoff[0]); ISSUE(g[1], nb, ldsoff[1]); }                 \
    if (DOMFMA) {                                                                          \
        __builtin_amdgcn_s_setprio(1);                                                     \
        _Pragma("unroll")                                                                  \
        for (int i = 0; i < 4; i++)                                                        \
            _Pragma("unroll")                                                              \
            for (int j = 0; j < 4; j++)                                                    \
                acc[i + 4][j] = __builtin_amdgcn_mfma_f32_16x16x32_bf16(                   \
                    afhi[(P) ^ 1][i], bfr[(P) ^ 1][j], acc[i + 4][j], 0, 0, 0);            \
        __builtin_amdgcn_s_setprio(0);                                                     \
    }                                                                                      \
    __builtin_amdgcn_s_barrier();                                                          \
} while (0)

// Region 2 of tile T: read afhi of tile T; issue DMA loads 2,3 for tile T+3; advance g;
// MFMA phase (T, lo-half); once-per-tile waitcnt; barrier.
#define R2(BUFC, BUFN, P, DOISS, WAITS) do {                                               \
    const u16* __restrict__ sb = S + (BUFC) * 16384;                                       \
    u16* nb = S + (BUFN) * 16384;                                                          \
    _Pragma("unroll")                                                                      \
    for (int i = 0; i < 4; i++) afhi[P][i] = *(const shortx8*)(sb + rdA + 4096 + i * 1024);\
    if (DOISS) {                                                                           \
        ISSUE(g[2], nb, ldsoff[2]); ISSUE(g[3], nb, ldsoff[3]);                            \
        _Pragma("unroll")                                                                  \
        for (int l = 0; l < 4; l++) g[l] += 32;                                            \
    }                                                                                      \
    __builtin_amdgcn_s_setprio(1);                                                         \
    _Pragma("unroll")                                                                      \
    for (int i = 0; i < 4; i++)                                                            \
        _Pragma("unroll")                                                                  \
        for (int j = 0; j < 4; j++)                                                        \
            acc[i][j] = __builtin_amdgcn_mfma_f32_16x16x32_bf16(                           \
                aflo[P][i], bfr[P][j], acc[i][j], 0, 0, 0);                                \
    __builtin_amdgcn_s_setprio(0);                                                         \
    WAITS;                                                                                 \
    __builtin_amdgcn_s_barrier();                                                          \
} while (0)

__global__ __launch_bounds__(512, 2)
void gemm256(const u16* __restrict__ At, const u16* __restrict__ Bt,
             const float* __restrict__ bias, float* __restrict__ out,
             int O, int I, int KT) {
    __shared__ u16 S[4 * 16384];          // 128 KiB: 4-buffer ring

    const int tid = threadIdx.x;
    const int nblk_n = O / 256;

    // bijective XCD swizzle
    int bid = blockIdx.x;
    const int nwg = gridDim.x;
    if ((nwg & 7) == 0) {
        const int q = nwg >> 3;
        bid = (bid & 7) * q + (bid >> 3);
    }
    const int mt = bid / nblk_n, nt = bid % nblk_n;

    const int w = tid >> 6, lane = tid & 63;
    const int wm = w >> 2, wn = w & 3;        // 2x4 wave grid; wave owns 128(M) x 64(O)
    const int l15 = lane & 15, l4 = lane >> 4;
    const int sw  = l15 & 7;                  // read-side un-swizzle

    // ds_read base offsets (u16 units); row stride = 64 u16 (128 B)
    const int rdA = (wm * 128 + l15) * 64 + ((l4 ^ sw) * 8);
    const int rdB = (wn * 64  + l15) * 64 + ((((l4 | 4) ^ sw)) * 8);

    // staging: 4 loads/thread/tile; load l covers chunk-slot s = (w*4+l)*64 + lane.
    const u16* g[4];
    int ldsoff[4];
    #pragma unroll
    for (int l = 0; l < 4; l++) {
        const int s   = (w * 4 + l) * 64 + lane;
        const int row = s >> 3;
        const int k   = (s & 7) ^ (row & 7);
        ldsoff[l] = (w * 4 + l) * 512 + lane * 8;      // lane-linear 16B slots (u16 units)
        g[l] = (k < 4) ? (At + (size_t)(mt * 256 + row) * I + k * 8)
                       : (Bt + (size_t)(nt * 256 + row) * I + (k - 4) * 8);
    }

    floatx4 acc[8][4];
    #pragma unroll
    for (int i = 0; i < 8; i++)
        #pragma unroll
        for (int j = 0; j < 4; j++)
            acc[i][j] = (floatx4){0.f, 0.f, 0.f, 0.f};

    shortx8 aflo[2][4], afhi[2][4], bfr[2][4];

    // prologue: stage tiles 0,1,2; wait tile 0 (tiles 1,2 stay in flight)
    #pragma unroll
    for (int p = 0; p < 3; p++) {
        u16* sb = &S[p * 16384];
        #pragma unroll
        for (int l = 0; l < 4; l++)
            ISSUE(g[l], sb, ldsoff[l]);
        #pragma unroll
        for (int l = 0; l < 4; l++) g[l] += 32;
    }
    asm volatile("s_waitcnt vmcnt(8)" ::: "memory");
    __builtin_amdgcn_s_barrier();

    // tile 0 (buf 0, parity 0): fills the register pipeline; no hi-phase MFMA yet
    R1(0, 3, 0, 1, 0);
    R2(0, 3, 0, 1, VM8L);

    // steady state: tiles 1..KT-4 in 4-tile unroll (parities 1,0,1,0; bufs 1,2,3,0)
    const int iters = (KT - 4) >> 2;
    for (int it = 0; it < iters; ++it) {
        R1(1, 0, 1, 1, 1); R2(1, 0, 1, 1, VM8L);
        R1(2, 1, 0, 1, 1); R2(2, 1, 0, 1, VM8L);
        R1(3, 2, 1, 1, 1); R2(3, 2, 1, 1, VM8L);
        R1(0, 3, 0, 1, 1); R2(0, 3, 0, 1, VM8L);
    }

    // epilogue tiles KT-3, KT-2, KT-1 (parities 1,0,1; bufs 1,2,3): drain
    R1(1, 0, 1, 0, 1); R2(1, 0, 1, 0, VM4L);
    R1(2, 1, 0, 0, 1); R2(2, 1, 0, 0, VM0L);
    R1(3, 2, 1, 0, 1); R2(3, 2, 1, 0, (void)0);

    // final hi-phase of last tile (parity 1), register-only
    __builtin_amdgcn_s_setprio(1);
    #pragma unroll
    for (int i = 0; i < 4; i++)
        #pragma unroll
        for (int j = 0; j < 4; j++)
            acc[i + 4][j] = __builtin_amdgcn_mfma_f32_16x16x32_bf16(
                afhi[1][i], bfr[1][j], acc[i + 4][j], 0, 0, 0);
    __builtin_amdgcn_s_setprio(0);

    #pragma unroll
    for (int j = 0; j < 4; j++) {
        int col  = nt * 256 + wn * 64 + j * 16 + l15;
        float bv = bias[col];
        #pragma unroll
        for (int i = 0; i < 8; i++) {
            int rowb = mt * 256 + wm * 128 + i * 16 + l4 * 4;
            #pragma unroll
            for (int r = 0; r < 4; r++)
                out[(size_t)(rowb + r) * O + col] = acc[i][j][r] + bv;
        }
    }
}

// ============ round-0 128x128 single-buffer GEMM (shape fallback, proven 130 us) ============
__global__ __launch_bounds__(THREADS, 2)
void gemm_bf16(const u16* __restrict__ At, const u16* __restrict__ Bt,
               const float* __restrict__ bias, float* __restrict__ out,
               int O, int I, int KT) {
    __shared__ u16 As[CHUNK];
    __shared__ u16 Bs[CHUNK];

    const int tid = threadIdx.x;
    const int nblk_n = O / TILE;
    const int mt = blockIdx.x / nblk_n;
    const int nt = blockIdx.x % nblk_n;
    const int w = tid >> 6, lane = tid & 63;
    const int wm = w >> 1, wn = w & 1;
    const int l15 = lane & 15, l4 = lane >> 4;
    const int sw  = l15 & 7;

    const int sr = tid >> 3;
    const int sc = (tid & 7) ^ (sr & 7);

    floatx4 acc[4][4];
    #pragma unroll
    for (int i = 0; i < 4; i++)
        #pragma unroll
        for (int j = 0; j < 4; j++)
            acc[i][j] = (floatx4){0.f, 0.f, 0.f, 0.f};

    const u16* gaBase = At + ((size_t)(mt * TILE) + sr) * I + sc * 8;
    const u16* gbBase = Bt + ((size_t)(nt * TILE) + sr) * I + sc * 8;

    for (int kt = 0; kt < KT; kt++) {
        const u16* ga = gaBase + kt * BK;
        const u16* gb = gbBase + kt * BK;
        __syncthreads();
        #pragma unroll
        for (int it = 0; it < 4; it++) {
            const int ldsOff = it * 2048 + tid * 8;
            const size_t gOff = (size_t)(it * 32) * I;
            __builtin_amdgcn_global_load_lds((const __attribute__((address_space(1))) u32*)(ga + gOff),
                                             (__attribute__((address_space(3))) u32*)(As + ldsOff),
                                             16, 0, 0);
            __builtin_amdgcn_global_load_lds((const __attribute__((address_space(1))) u32*)(gb + gOff),
                                             (__attribute__((address_space(3))) u32*)(Bs + ldsOff),
                                             16, 0, 0);
        }
        __syncthreads();

        #pragma unroll
        for (int ks = 0; ks < 2; ks++) {
            shortx8 af[4], bfr2[4];
            #pragma unroll
            for (int i = 0; i < 4; i++)
                af[i] = *(const shortx8*)(&As[(wm * 64 + i * 16 + l15) * BK + ((ks * 4 + l4) ^ sw) * 8]);
            #pragma unroll
            for (int j = 0; j < 4; j++)
                bfr2[j] = *(const shortx8*)(&Bs[(wn * 64 + j * 16 + l15) * BK + ((ks * 4 + l4) ^ sw) * 8]);
            #pragma unroll
            for (int i = 0; i < 4; i++)
                #pragma unroll
                for (int j = 0; j < 4; j++)
                    acc[i][j] = __builtin_amdgcn_mfma_f32_16x16x32_bf16(af[i], bfr2[j], acc[i][j], 0, 0, 0);
        }
    }

    #pragma unroll
    for (int j = 0; j < 4; j++) {
        int col  = nt * TILE + wn * 64 + j * 16 + l15;
        float bv = bias[col];
        #pragma unroll
        for (int i = 0; i < 4; i++) {
            int rowb = mt * TILE + wm * 64 + i * 16 + l4 * 4;
            #pragma unroll
            for (int r = 0; r < 4; r++)
                out[(size_t)(rowb + r) * O + col] = acc[i][j][r] + bv;
        }
    }
}

// ======================= fallback (fused) if ws too small =======================
#define LDA 72
__global__ __launch_bounds__(THREADS, 2)
void wql_fused(const float* __restrict__ x, const int* __restrict__ pw,
               const float* __restrict__ scale, const int* __restrict__ pzp,
               const float* __restrict__ bias, float* __restrict__ out,
               int M, int O, int I, int ng)
{
    __shared__ unsigned short As[TILE * LDA];
    __shared__ unsigned short Bs[TILE * LDA];
    const int tid = threadIdx.x;
    const int nblk_n = O / TILE;
    const int mt = blockIdx.x / nblk_n, nt = blockIdx.x % nblk_n;
    const int w = tid >> 6, lane = tid & 63;
    const int wm = w >> 1, wn = w & 1;
    const int l15 = lane & 15, l4 = lane >> 4;
    const int pw_rowlen = I / 8, zp_rowlen = (ng + 7) / 8, GS = I / ng;

    floatx4 acc[4][4];
    #pragma unroll
    for (int i = 0; i < 4; i++)
        #pragma unroll
        for (int j = 0; j < 4; j++) acc[i][j] = (floatx4){0.f, 0.f, 0.f, 0.f};

    const int nk = I / BK;
    for (int kt = 0; kt < nk; kt++) {
        __syncthreads();
        #pragma unroll
        for (int it = 0; it < 8; it++) {
            int f = tid + it * THREADS;
            int row = f >> 4, seg = f & 15;
            const float4 v = *(const float4*)(x + (size_t)(mt * TILE + row) * I + kt * BK + seg * 4);
            ushortx4 b;
            b.x = f2bf(v.x); b.y = f2bf(v.y); b.z = f2bf(v.z); b.w = f2bf(v.w);
            *(ushortx4*)(&As[row * LDA + seg * 4]) = b;
        }
        const int g = (kt * BK) / GS;
        #pragma unroll
        for (int it = 0; it < 4; it++) {
            int e = tid + it * THREADS;
            int row = e >> 3, c = e & 7;
            int o = nt * TILE + row;
            int wq = pw[(size_t)o * pw_rowlen + kt * (BK / 8) + c];
            float s = scale[o * ng + g];
            int zpw = pzp[o * zp_rowlen + (g >> 3)];
            int zp = (zpw >> ((g & 7) * 4)) & 15;
            shortx8 b;
            #pragma unroll
            for (int j = 0; j < 8; j++) {
                int nib = (wq >> (4 * j)) & 15;
                b[j] = (short)f2bf((float)(nib - zp) * s);
            }
            *(shortx8*)(&Bs[row * LDA + c * 8]) = b;
        }
        __syncthreads();
        #pragma unroll
        for (int ks = 0; ks < 2; ks++) {
            shortx8 af[4], bfr2[4];
            #pragma unroll
            for (int i = 0; i < 4; i++)
                af[i] = *(const shortx8*)(&As[(wm * 64 + i * 16 + l15) * LDA + ks * 32 + l4 * 8]);
            #pragma unroll
            for (int j = 0; j < 4; j++)
                bfr2[j] = *(const shortx8*)(&Bs[(wn * 64 + j * 16 + l15) * LDA + ks * 32 + l4 * 8]);
            #pragma unroll
            for (int i = 0; i < 4; i++)
                #pragma unroll
                for (int j = 0; j < 4; j++)
                    acc[i][j] = __builtin_amdgcn_mfma_f32_16x16x32_bf16(af[i], bfr2[j], acc[i][j], 0, 0, 0);
        }
    }
    #pragma unroll
    for (int j = 0; j < 4; j++) {
        int col = nt * TILE + wn * 64 + j * 16 + l15;
        float bv = bias[col];
        #pragma unroll
        for (int i = 0; i < 4; i++) {
            int rowb = mt * TILE + wm * 64 + i * 16 + l4 * 4;
            #pragma unroll
            for (int r = 0; r < 4; r++)
                out[(size_t)(rowb + r) * O + col] = acc[i][j][r] + bv;
        }
    }
}

extern "C" void kernel_launch(void* const* d_in, const int* in_sizes, int n_in,
                              void* d_out, int out_size, void* d_ws, size_t ws_size,
                              hipStream_t stream) {
    const float* x     = (const float*)d_in[0];
    const int*   pw    = (const int*)d_in[1];
    const float* scale = (const float*)d_in[2];
    const int*   pzp   = (const int*)d_in[3];
    const float* bias  = (const float*)d_in[4];
    float*       out   = (float*)d_out;

    const int O  = in_sizes[4];                   // 4096
    const int ng = in_sizes[2] / O;               // 32
    const int I  = (in_sizes[1] / O) * 8;         // 4096
    const int M  = in_sizes[0] / I;               // 4096
    int lsSeg = 0; { int v = I >> 3; while ((1 << lsSeg) < v) lsSeg++; }      // log2(I/8)
    int lsG = 0;   { int v = (I / ng) >> 3; while ((1 << lsG) < v) lsG++; }   // log2(GS/8)

    const size_t need = ((size_t)M * I + (size_t)O * I) * sizeof(u16);  // 64 MB
    if (ws_size >= need) {
        u16* At = (u16*)d_ws;
        u16* Bt = At + (size_t)M * I;
        prep_kernel<<<dim3(2048), THREADS, 0, stream>>>(x, pw, scale, pzp, At, Bt, M, O, I, ng, lsSeg, lsG);
        const int KT32 = I / 32;
        const bool ok256 = (M % 256 == 0) && (O % 256 == 0) && (I % 128 == 0) && (KT32 >= 8) && ((KT32 & 3) == 0);
        if (ok256) {
            gemm256<<<dim3((M / 256) * (O / 256)), 512, 0, stream>>>(At, Bt, bias, out, O, I, KT32);
        } else {
            gemm_bf16<<<dim3((M / TILE) * (O / TILE)), THREADS, 0, stream>>>(At, Bt, bias, out, O, I, I / BK);
        }
    } else {
        wql_fused<<<dim3((M / TILE) * (O / TILE)), THREADS, 0, stream>>>(x, pw, scale, pzp, bias, out, M, O, I, ng);
    }
}